// Round 4
// baseline (252.354 us; speedup 1.0000x reference)
//
#include <hip/hip_runtime.h>
#include <stdint.h>

#define NB 262144
#define D 128
#define K 10

#define QBLOCKS 2048
#define QTHREADS 256
// 4 lanes per row: rows/iter = QBLOCKS*QTHREADS/4 = 131072 -> 2 iters
#define QITERS (NB * 4 / (QBLOCKS * QTHREADS))

// ---------------- Kernel 1: q + column partial sums ----------------
// Row r is owned by 4 consecutive lanes (sub = 0..3); lane sub covers
// cols {k*16 + sub*4 .. +3} for k=0..7. A wave's z-load = 16 rows x 64B
// contiguous segments (coalesced); centers broadcast from LDS.
__global__ __launch_bounds__(QTHREADS) void qkern(
    const float* __restrict__ z, const float* __restrict__ centers,
    float* __restrict__ qout, float* __restrict__ f) {
  __shared__ float c_lds[K * D];   // 5 KB
  __shared__ float red[4][K];

  const int t = threadIdx.x;
  const int w = t >> 6;
  const int lane = t & 63;

  for (int i = t; i < K * D; i += QTHREADS) c_lds[i] = centers[i];
  __syncthreads();

  float colp[K];
#pragma unroll
  for (int j = 0; j < K; ++j) colp[j] = 0.f;

  for (int it = 0; it < QITERS; ++it) {
    const int g = (blockIdx.x + it * QBLOCKS) * QTHREADS + t;
    const int r = g >> 2;
    const int sub = g & 3;

    float acc[K];
#pragma unroll
    for (int j = 0; j < K; ++j) acc[j] = 0.f;

    const float* zr = z + (size_t)r * D + sub * 4;
#pragma unroll
    for (int k = 0; k < 8; ++k) {
      float4 zv = *reinterpret_cast<const float4*>(&zr[k * 16]);
#pragma unroll
      for (int j = 0; j < K; ++j) {
        float4 cv = *reinterpret_cast<const float4*>(&c_lds[j * D + k * 16 + sub * 4]);
        float dx = zv.x - cv.x; acc[j] = fmaf(dx, dx, acc[j]);
        float dy = zv.y - cv.y; acc[j] = fmaf(dy, dy, acc[j]);
        float dz = zv.z - cv.z; acc[j] = fmaf(dz, dz, acc[j]);
        float dw = zv.w - cv.w; acc[j] = fmaf(dw, dw, acc[j]);
      }
    }
    // sum the 4 sub-lane partials -> full ||z_r - mu_j||^2 on sub==0
#pragma unroll
    for (int j = 0; j < K; ++j) {
      acc[j] += __shfl_xor(acc[j], 1);
      acc[j] += __shfl_xor(acc[j], 2);
    }

    if (sub == 0) {
      float qu[K];
      float srow = 0.f;
#pragma unroll
      for (int j = 0; j < K; ++j) {
        qu[j] = 1.0f / (1.0f + acc[j]);
        srow += qu[j];
      }
      float inv = 1.0f / srow;
#pragma unroll
      for (int j = 0; j < K; ++j) {
        qu[j] *= inv;
        colp[j] += qu[j];
      }
      float* qo = qout + (size_t)r * K;
      *reinterpret_cast<float4*>(&qo[0]) = make_float4(qu[0], qu[1], qu[2], qu[3]);
      *reinterpret_cast<float4*>(&qo[4]) = make_float4(qu[4], qu[5], qu[6], qu[7]);
      *reinterpret_cast<float2*>(&qo[8]) = make_float2(qu[8], qu[9]);
    }
  }

  // colp lives only on sub==0 lanes (others 0): offsets 4,8,16,32 sum them
#pragma unroll
  for (int j = 0; j < K; ++j) {
    colp[j] += __shfl_xor(colp[j], 4);
    colp[j] += __shfl_xor(colp[j], 8);
    colp[j] += __shfl_xor(colp[j], 16);
    colp[j] += __shfl_xor(colp[j], 32);
  }
  if (lane == 0) {
#pragma unroll
    for (int j = 0; j < K; ++j) red[w][j] = colp[j];
  }
  __syncthreads();
  if (t < K) {
    float s = red[0][t] + red[1][t] + red[2][t] + red[3][t];
    atomicAdd(&f[t], s);
  }
}

// ---------------- Kernel 2: p from q, f ----------------
__global__ __launch_bounds__(256) void pkern(
    const float* __restrict__ q, const float* __restrict__ f,
    float* __restrict__ p) {
  int row = blockIdx.x * 256 + threadIdx.x;
  const float* qr = q + (size_t)row * K;
  float wv[K];
  float s = 0.f;
#pragma unroll
  for (int j = 0; j < K; j += 2) {
    float2 qq = *reinterpret_cast<const float2*>(&qr[j]);
    wv[j] = qq.x * qq.x / f[j];
    wv[j + 1] = qq.y * qq.y / f[j + 1];
    s += wv[j] + wv[j + 1];
  }
  float inv = 1.0f / s;
  float* pr = p + (size_t)row * K;
#pragma unroll
  for (int j = 0; j < K; j += 2) {
    *reinterpret_cast<float2*>(&pr[j]) = make_float2(wv[j] * inv, wv[j + 1] * inv);
  }
}

extern "C" void kernel_launch(void* const* d_in, const int* in_sizes, int n_in,
                              void* d_out, int out_size, void* d_ws, size_t ws_size,
                              hipStream_t stream) {
  const float* z = (const float*)d_in[0];
  const float* centers = (const float*)d_in[1];
  float* out = (float*)d_out;            // q at [0, NB*K), p at [NB*K, 2*NB*K)
  float* f = (float*)d_ws;               // K column sums

  hipMemsetAsync(d_ws, 0, K * sizeof(float), stream);
  qkern<<<QBLOCKS, QTHREADS, 0, stream>>>(z, centers, out, f);
  pkern<<<NB / 256, 256, 0, stream>>>(out, f, out + (size_t)NB * K);
}

// Round 7
// 210.081 us; speedup vs baseline: 1.2012x; 1.2012x over previous
//
#include <hip/hip_runtime.h>
#include <stdint.h>

#define NB 262144
#define D 128
#define K 10

#define QBLOCKS 1024
#define QTHREADS 256
#define ROWS_PER_BLOCK (NB / QBLOCKS)               // 256
#define TILES_PER_WAVE (ROWS_PER_BLOCK / 4 / 16)    // 4

typedef __attribute__((ext_vector_type(8))) __bf16 bf16x8;
typedef __attribute__((ext_vector_type(4))) float f32x4;

__device__ inline __bf16 f2bf(float x) {
  unsigned u = __builtin_bit_cast(unsigned, x);
  u += 0x7fffu + ((u >> 16) & 1u);               // RNE
  unsigned short s = (unsigned short)(u >> 16);
  return __builtin_bit_cast(__bf16, s);
}

__device__ inline bf16x8 make_frag(float4 lo, float4 hi) {
  bf16x8 a;
  a[0] = f2bf(lo.x); a[1] = f2bf(lo.y); a[2] = f2bf(lo.z); a[3] = f2bf(lo.w);
  a[4] = f2bf(hi.x); a[5] = f2bf(hi.y); a[6] = f2bf(hi.z); a[7] = f2bf(hi.w);
  return a;
}

// ---------------- Kernel 1: q + column partial sums (MFMA) ----------------
// d^2 = ||z||^2 - 2 z.mu + ||mu||^2 ; z.mu^T via mfma_f32_16x16x32_bf16.
// Per 16-row tile: A = z[16 x 128] (4 K-chunks), B = mu^T[128 x 16] (cols>=K zero).
// Frag layout (m89-verified C/D; standard A/B): lane l: n=l&15, g=l>>4.
//   A[m=n][k=g*8+j+32c], B[k=g*8+j+32c][col=n], C[row=g*4+i][col=n].
__global__ __launch_bounds__(QTHREADS) void qkern(
    const float* __restrict__ z, const float* __restrict__ centers,
    float* __restrict__ qout, float* __restrict__ f) {
  __shared__ float red[4][16];

  const int t = threadIdx.x;
  const int w = t >> 6;
  const int lane = t & 63;
  const int n = lane & 15;   // output col (cluster), 10..15 padded
  const int g = lane >> 4;   // k-group

  // --- B fragments (centers) + ||mu_n||^2, once per block, all in regs ---
  bf16x8 bfrag[4];
  float mu2 = 0.f;
  if (n < K) {
    const float* cp = centers + n * D;
#pragma unroll
    for (int c = 0; c < 4; ++c) {
      float4 lo = *reinterpret_cast<const float4*>(cp + c * 32 + g * 8);
      float4 hi = *reinterpret_cast<const float4*>(cp + c * 32 + g * 8 + 4);
      bfrag[c] = make_frag(lo, hi);
    }
#pragma unroll
    for (int d4 = 0; d4 < 32; ++d4) {
      float4 v = *reinterpret_cast<const float4*>(cp + d4 * 4);
      mu2 = fmaf(v.x, v.x, mu2); mu2 = fmaf(v.y, v.y, mu2);
      mu2 = fmaf(v.z, v.z, mu2); mu2 = fmaf(v.w, v.w, mu2);
    }
  } else {
    unsigned short zb = 0;
#pragma unroll
    for (int c = 0; c < 4; ++c)
#pragma unroll
      for (int j = 0; j < 8; ++j) bfrag[c][j] = __builtin_bit_cast(__bf16, zb);
  }

  float colp = 0.f;
  const int wbase = blockIdx.x * ROWS_PER_BLOCK + w * (TILES_PER_WAVE * 16);

  for (int tile = 0; tile < TILES_PER_WAVE; ++tile) {
    const int rbase = wbase + tile * 16;
    const float* zr = z + (size_t)(rbase + n) * D + g * 8;

    float4 zf[8];
#pragma unroll
    for (int c = 0; c < 4; ++c) {
      zf[2 * c]     = *reinterpret_cast<const float4*>(zr + c * 32);
      zf[2 * c + 1] = *reinterpret_cast<const float4*>(zr + c * 32 + 4);
    }

    // ||z_row||^2 : per-lane partial over its 32 cols, reduce across 4 groups
    float z2 = 0.f;
#pragma unroll
    for (int q8 = 0; q8 < 8; ++q8) {
      z2 = fmaf(zf[q8].x, zf[q8].x, z2); z2 = fmaf(zf[q8].y, zf[q8].y, z2);
      z2 = fmaf(zf[q8].z, zf[q8].z, z2); z2 = fmaf(zf[q8].w, zf[q8].w, z2);
    }
    z2 += __shfl_xor(z2, 16);
    z2 += __shfl_xor(z2, 32);   // all lanes: ||z_{rbase+n}||^2

    f32x4 acc = {0.f, 0.f, 0.f, 0.f};
#pragma unroll
    for (int c = 0; c < 4; ++c) {
      bf16x8 a = make_frag(zf[2 * c], zf[2 * c + 1]);
      acc = __builtin_amdgcn_mfma_f32_16x16x32_bf16(a, bfrag[c], acc, 0, 0, 0);
    }

#pragma unroll
    for (int i = 0; i < 4; ++i) {
      float z2i = __shfl(z2, g * 4 + i);          // ||z_{rbase+g*4+i}||^2
      float d2 = z2i - 2.f * acc[i] + mu2;
      float qu = (n < K) ? 1.0f / (1.0f + d2) : 0.f;
      float rs = qu;
      rs += __shfl_xor(rs, 1); rs += __shfl_xor(rs, 2);
      rs += __shfl_xor(rs, 4); rs += __shfl_xor(rs, 8);
      float qv = qu * (1.0f / rs);
      if (n < K) qout[(size_t)(rbase + g * 4 + i) * K + n] = qv;
      colp += qv;
    }
  }

  // column partials: lanes with equal n hold same col -> sum groups, then block
  colp += __shfl_xor(colp, 16);
  colp += __shfl_xor(colp, 32);
  if (lane < 16) red[w][lane] = colp;
  __syncthreads();
  if (t < K) atomicAdd(&f[t], red[0][t] + red[1][t] + red[2][t] + red[3][t]);
}

// ---------------- Kernel 2: p from q, f ----------------
__global__ __launch_bounds__(256) void pkern(
    const float* __restrict__ q, const float* __restrict__ f,
    float* __restrict__ p) {
  int row = blockIdx.x * 256 + threadIdx.x;
  const float* qr = q + (size_t)row * K;
  float wv[K];
  float s = 0.f;
#pragma unroll
  for (int j = 0; j < K; j += 2) {
    float2 qq = *reinterpret_cast<const float2*>(&qr[j]);
    wv[j] = qq.x * qq.x / f[j];
    wv[j + 1] = qq.y * qq.y / f[j + 1];
    s += wv[j] + wv[j + 1];
  }
  float inv = 1.0f / s;
  float* pr = p + (size_t)row * K;
#pragma unroll
  for (int j = 0; j < K; j += 2) {
    *reinterpret_cast<float2*>(&pr[j]) = make_float2(wv[j] * inv, wv[j + 1] * inv);
  }
}

extern "C" void kernel_launch(void* const* d_in, const int* in_sizes, int n_in,
                              void* d_out, int out_size, void* d_ws, size_t ws_size,
                              hipStream_t stream) {
  const float* z = (const float*)d_in[0];
  const float* centers = (const float*)d_in[1];
  float* out = (float*)d_out;            // q at [0, NB*K), p at [NB*K, 2*NB*K)
  float* f = (float*)d_ws;               // K column sums

  hipMemsetAsync(d_ws, 0, K * sizeof(float), stream);
  qkern<<<QBLOCKS, QTHREADS, 0, stream>>>(z, centers, out, f);
  pkern<<<NB / 256, 256, 0, stream>>>(out, f, out + (size_t)NB * K);
}

// Round 8
// 209.136 us; speedup vs baseline: 1.2067x; 1.0045x over previous
//
#include <hip/hip_runtime.h>
#include <stdint.h>

#define NB 262144
#define D 128
#define K 10

#define QBLOCKS 1024
#define QTHREADS 256
#define ROWS_PER_BLOCK (NB / QBLOCKS)               // 256
#define TILES_PER_WAVE (ROWS_PER_BLOCK / 4 / 16)    // 4

typedef __attribute__((ext_vector_type(8))) __bf16 bf16x8;
typedef __attribute__((ext_vector_type(4))) float f32x4;

__device__ inline bf16x8 make_frag(const float4 lo, const float4 hi) {
  bf16x8 a;
  a[0] = (__bf16)lo.x; a[1] = (__bf16)lo.y; a[2] = (__bf16)lo.z; a[3] = (__bf16)lo.w;
  a[4] = (__bf16)hi.x; a[5] = (__bf16)hi.y; a[6] = (__bf16)hi.z; a[7] = (__bf16)hi.w;
  return a;
}

__device__ inline void load_zf(const float* zr, float4* zf) {
#pragma unroll
  for (int c = 0; c < 4; ++c) {
    zf[2 * c]     = *reinterpret_cast<const float4*>(zr + c * 32);
    zf[2 * c + 1] = *reinterpret_cast<const float4*>(zr + c * 32 + 4);
  }
}

// ---------------- Kernel 1: q + column partial sums (MFMA, pipelined) ------
// d^2 = ||z||^2 - 2 z.mu + ||mu||^2 ; z.mu^T via mfma_f32_16x16x32_bf16.
// lane l: n=l&15 (cluster col, 10..15 zero-pad), g=l>>4 (k-group).
// A[m=n][k=g*8+j+32c], B[k][col=n], C[row=g*4+i][col=n] (m89-verified).
// 2-deep zf double-buffer: tile t+1 loads issue before tile t compute,
// so HBM latency hides under cvt+MFMA+epilogue; z2 broadcasts hoisted
// pre-MFMA so their DS latency hides under the matrix pipe.
__global__ __launch_bounds__(QTHREADS) void qkern(
    const float* __restrict__ z, const float* __restrict__ centers,
    float* __restrict__ qout, float* __restrict__ f) {
  __shared__ float red[4][16];

  const int t = threadIdx.x;
  const int w = t >> 6;
  const int lane = t & 63;
  const int n = lane & 15;
  const int g = lane >> 4;

  // --- B fragments (centers) + ||mu_n||^2, once per block, in regs ---
  bf16x8 bfrag[4];
  float mu2 = 0.f;
  if (n < K) {
    const float* cp = centers + n * D;
#pragma unroll
    for (int c = 0; c < 4; ++c) {
      float4 lo = *reinterpret_cast<const float4*>(cp + c * 32 + g * 8);
      float4 hi = *reinterpret_cast<const float4*>(cp + c * 32 + g * 8 + 4);
      bfrag[c] = make_frag(lo, hi);
    }
#pragma unroll
    for (int d4 = 0; d4 < 32; ++d4) {
      float4 v = *reinterpret_cast<const float4*>(cp + d4 * 4);
      mu2 = fmaf(v.x, v.x, mu2); mu2 = fmaf(v.y, v.y, mu2);
      mu2 = fmaf(v.z, v.z, mu2); mu2 = fmaf(v.w, v.w, mu2);
    }
  } else {
    unsigned short zb = 0;
#pragma unroll
    for (int c = 0; c < 4; ++c)
#pragma unroll
      for (int j = 0; j < 8; ++j) bfrag[c][j] = __builtin_bit_cast(__bf16, zb);
  }

  float colp = 0.f;
  const int wbase = blockIdx.x * ROWS_PER_BLOCK + w * (TILES_PER_WAVE * 16);

  float4 zfA[8], zfB[8];
  load_zf(z + (size_t)(wbase + n) * D + g * 8, zfA);

#pragma unroll
  for (int tile = 0; tile < TILES_PER_WAVE; ++tile) {
    const float4* cur = (tile & 1) ? zfB : zfA;
    float4* nxt = (tile & 1) ? zfA : zfB;
    const int rbase = wbase + tile * 16;

    // issue next tile's loads first — latency hidden under this tile's work
    if (tile + 1 < TILES_PER_WAVE)
      load_zf(z + (size_t)(rbase + 16 + n) * D + g * 8, nxt);

    // ||z_row||^2 partials + group reduce
    float z2 = 0.f;
#pragma unroll
    for (int q8 = 0; q8 < 8; ++q8) {
      z2 = fmaf(cur[q8].x, cur[q8].x, z2); z2 = fmaf(cur[q8].y, cur[q8].y, z2);
      z2 = fmaf(cur[q8].z, cur[q8].z, z2); z2 = fmaf(cur[q8].w, cur[q8].w, z2);
    }
    z2 += __shfl_xor(z2, 16);
    z2 += __shfl_xor(z2, 32);          // all lanes: ||z_{rbase+n}||^2

    // hoisted broadcasts (4 independent ds_bpermute; hide under cvt+MFMA)
    float z2i[4];
#pragma unroll
    for (int i = 0; i < 4; ++i) z2i[i] = __shfl(z2, g * 4 + i);

    f32x4 acc = {0.f, 0.f, 0.f, 0.f};
#pragma unroll
    for (int c = 0; c < 4; ++c) {
      bf16x8 a = make_frag(cur[2 * c], cur[2 * c + 1]);
      acc = __builtin_amdgcn_mfma_f32_16x16x32_bf16(a, bfrag[c], acc, 0, 0, 0);
    }

#pragma unroll
    for (int i = 0; i < 4; ++i) {
      float d2 = z2i[i] - 2.f * acc[i] + mu2;
      float qu = (n < K) ? 1.0f / (1.0f + d2) : 0.f;
      float rs = qu;
      rs += __shfl_xor(rs, 1); rs += __shfl_xor(rs, 2);
      rs += __shfl_xor(rs, 4); rs += __shfl_xor(rs, 8);
      float qv = qu * (1.0f / rs);
      if (n < K) qout[(size_t)(rbase + g * 4 + i) * K + n] = qv;
      colp += qv;
    }
  }

  // column partials: sum across the 4 g-copies of each col, then block
  colp += __shfl_xor(colp, 16);
  colp += __shfl_xor(colp, 32);
  if (lane < 16) red[w][lane] = colp;
  __syncthreads();
  if (t < K) atomicAdd(&f[t], red[0][t] + red[1][t] + red[2][t] + red[3][t]);
}

// ---------------- Kernel 2: p from q, f ----------------
__global__ __launch_bounds__(256) void pkern(
    const float* __restrict__ q, const float* __restrict__ f,
    float* __restrict__ p) {
  int row = blockIdx.x * 256 + threadIdx.x;
  const float* qr = q + (size_t)row * K;
  float wv[K];
  float s = 0.f;
#pragma unroll
  for (int j = 0; j < K; j += 2) {
    float2 qq = *reinterpret_cast<const float2*>(&qr[j]);
    wv[j] = qq.x * qq.x / f[j];
    wv[j + 1] = qq.y * qq.y / f[j + 1];
    s += wv[j] + wv[j + 1];
  }
  float inv = 1.0f / s;
  float* pr = p + (size_t)row * K;
#pragma unroll
  for (int j = 0; j < K; j += 2) {
    *reinterpret_cast<float2*>(&pr[j]) = make_float2(wv[j] * inv, wv[j + 1] * inv);
  }
}

extern "C" void kernel_launch(void* const* d_in, const int* in_sizes, int n_in,
                              void* d_out, int out_size, void* d_ws, size_t ws_size,
                              hipStream_t stream) {
  const float* z = (const float*)d_in[0];
  const float* centers = (const float*)d_in[1];
  float* out = (float*)d_out;            // q at [0, NB*K), p at [NB*K, 2*NB*K)
  float* f = (float*)d_ws;               // K column sums

  hipMemsetAsync(d_ws, 0, K * sizeof(float), stream);
  qkern<<<QBLOCKS, QTHREADS, 0, stream>>>(z, centers, out, f);
  pkern<<<NB / 256, 256, 0, stream>>>(out, f, out + (size_t)NB * K);
}

// Round 9
// 206.759 us; speedup vs baseline: 1.2205x; 1.0115x over previous
//
#include <hip/hip_runtime.h>
#include <stdint.h>

#define NB 262144
#define D 128
#define K 10

#define ROWS_PER_BLOCK 128
#define QBLOCKS (NB / ROWS_PER_BLOCK)   // 2048
#define QTHREADS 256

typedef __attribute__((ext_vector_type(8))) __bf16 bf16x8;
typedef __attribute__((ext_vector_type(4))) float f32x4;

__device__ inline bf16x8 make_frag(const float4 lo, const float4 hi) {
  bf16x8 a;
  a[0] = (__bf16)lo.x; a[1] = (__bf16)lo.y; a[2] = (__bf16)lo.z; a[3] = (__bf16)lo.w;
  a[4] = (__bf16)hi.x; a[5] = (__bf16)hi.y; a[6] = (__bf16)hi.z; a[7] = (__bf16)hi.w;
  return a;
}

// ---------------- Kernel 1: q + column partial sums (transposed MFMA) ------
// C = mu . z^T : A = centers[16 x 128] (rows=clusters, >=K zero),
// B = z-tile[128 x 16] (cols = z-rows). C[row=cluster][col=z-row].
// lane l: n=l&15 (z-row in tile), g=l>>4. C: col=n, row=g*4+i (m89-verified).
// => lane n owns z-row n: z2 needs NO broadcast; rowsum = per-lane sum of its
// 4 cluster-values + xor16+xor32. DS ops/tile: 22 -> 4. Stores: float4.
__global__ __launch_bounds__(QTHREADS) void qkern(
    const float* __restrict__ z, const float* __restrict__ centers,
    float* __restrict__ qout, float* __restrict__ f) {
  __shared__ float red[4][16];

  const int t = threadIdx.x;
  const int w = t >> 6;
  const int lane = t & 63;
  const int n = lane & 15;   // z-row within tile / A-row (cluster) for A-frag
  const int g = lane >> 4;   // k-group

  // --- A fragments: centers row n (cluster n), bf16; + ||mu_n||^2 ---
  bf16x8 afrag[4];
  float mu2own = 0.f;
  if (n < K) {
    const float* cp = centers + n * D;
#pragma unroll
    for (int c = 0; c < 4; ++c) {
      float4 lo = *reinterpret_cast<const float4*>(cp + c * 32 + g * 8);
      float4 hi = *reinterpret_cast<const float4*>(cp + c * 32 + g * 8 + 4);
      afrag[c] = make_frag(lo, hi);
    }
#pragma unroll
    for (int d4 = 0; d4 < 32; ++d4) {
      float4 v = *reinterpret_cast<const float4*>(cp + d4 * 4);
      mu2own = fmaf(v.x, v.x, mu2own); mu2own = fmaf(v.y, v.y, mu2own);
      mu2own = fmaf(v.z, v.z, mu2own); mu2own = fmaf(v.w, v.w, mu2own);
    }
  } else {
    unsigned short zb = 0;
#pragma unroll
    for (int c = 0; c < 4; ++c)
#pragma unroll
      for (int j = 0; j < 8; ++j) afrag[c][j] = __builtin_bit_cast(__bf16, zb);
  }
  // mu2 for this lane's 4 clusters g*4+i (lanes >=10 shuffle-in 0 — harmless)
  float mu2[4];
#pragma unroll
  for (int i = 0; i < 4; ++i) mu2[i] = __shfl(mu2own, g * 4 + i);

  float colp[4] = {0.f, 0.f, 0.f, 0.f};
  const int wbase = blockIdx.x * ROWS_PER_BLOCK + w * 32;   // 2 tiles/wave

#pragma unroll
  for (int tile = 0; tile < 2; ++tile) {
    const int rbase = wbase + tile * 16;
    const float* zr = z + (size_t)(rbase + n) * D + g * 8;

    float4 zf[8];
#pragma unroll
    for (int c = 0; c < 4; ++c) {
      zf[2 * c]     = *reinterpret_cast<const float4*>(zr + c * 32);
      zf[2 * c + 1] = *reinterpret_cast<const float4*>(zr + c * 32 + 4);
    }

    // ||z_n||^2 : per-lane partial over its 32 elems, complete across g's
    float z2 = 0.f;
#pragma unroll
    for (int q8 = 0; q8 < 8; ++q8) {
      z2 = fmaf(zf[q8].x, zf[q8].x, z2); z2 = fmaf(zf[q8].y, zf[q8].y, z2);
      z2 = fmaf(zf[q8].z, zf[q8].z, z2); z2 = fmaf(zf[q8].w, zf[q8].w, z2);
    }
    z2 += __shfl_xor(z2, 16);
    z2 += __shfl_xor(z2, 32);          // lane now has full ||z_{rbase+n}||^2

    f32x4 acc = {0.f, 0.f, 0.f, 0.f};
#pragma unroll
    for (int c = 0; c < 4; ++c) {
      bf16x8 b = make_frag(zf[2 * c], zf[2 * c + 1]);
      acc = __builtin_amdgcn_mfma_f32_16x16x32_bf16(afrag[c], b, acc, 0, 0, 0);
    }

    // epilogue: all per-lane except one 2-step rowsum butterfly
    float qu[4];
    float s = 0.f;
#pragma unroll
    for (int i = 0; i < 4; ++i) {
      const int cl = g * 4 + i;
      float d2 = z2 - 2.f * acc[i] + mu2[i];
      qu[i] = (cl < K) ? 1.0f / (1.0f + d2) : 0.f;
      s += qu[i];
    }
    s += __shfl_xor(s, 16);
    s += __shfl_xor(s, 32);            // full row sum
    float inv = 1.0f / s;
#pragma unroll
    for (int i = 0; i < 4; ++i) { qu[i] *= inv; colp[i] += qu[i]; }

    float* qo = qout + (size_t)(rbase + n) * K;
    if (g < 2)
      *reinterpret_cast<float4*>(qo + g * 4) = make_float4(qu[0], qu[1], qu[2], qu[3]);
    else if (g == 2)
      *reinterpret_cast<float2*>(qo + 8) = make_float2(qu[0], qu[1]);
  }

  // column sums: reduce across the 16 rows (n) within the wave, then block
#pragma unroll
  for (int i = 0; i < 4; ++i) {
    colp[i] += __shfl_xor(colp[i], 1);
    colp[i] += __shfl_xor(colp[i], 2);
    colp[i] += __shfl_xor(colp[i], 4);
    colp[i] += __shfl_xor(colp[i], 8);
  }
  if (n == 0) {                         // one lane per g-group
#pragma unroll
    for (int i = 0; i < 4; ++i) red[w][g * 4 + i] = colp[i];
  }
  __syncthreads();
  if (t < K) atomicAdd(&f[t], red[0][t] + red[1][t] + red[2][t] + red[3][t]);
}

// ---------------- Kernel 2: p from q, f (unchanged — isolate one variable) --
__global__ __launch_bounds__(256) void pkern(
    const float* __restrict__ q, const float* __restrict__ f,
    float* __restrict__ p) {
  int row = blockIdx.x * 256 + threadIdx.x;
  const float* qr = q + (size_t)row * K;
  float wv[K];
  float s = 0.f;
#pragma unroll
  for (int j = 0; j < K; j += 2) {
    float2 qq = *reinterpret_cast<const float2*>(&qr[j]);
    wv[j] = qq.x * qq.x / f[j];
    wv[j + 1] = qq.y * qq.y / f[j + 1];
    s += wv[j] + wv[j + 1];
  }
  float inv = 1.0f / s;
  float* pr = p + (size_t)row * K;
#pragma unroll
  for (int j = 0; j < K; j += 2) {
    *reinterpret_cast<float2*>(&pr[j]) = make_float2(wv[j] * inv, wv[j + 1] * inv);
  }
}

extern "C" void kernel_launch(void* const* d_in, const int* in_sizes, int n_in,
                              void* d_out, int out_size, void* d_ws, size_t ws_size,
                              hipStream_t stream) {
  const float* z = (const float*)d_in[0];
  const float* centers = (const float*)d_in[1];
  float* out = (float*)d_out;            // q at [0, NB*K), p at [NB*K, 2*NB*K)
  float* f = (float*)d_ws;               // K column sums

  hipMemsetAsync(d_ws, 0, K * sizeof(float), stream);
  qkern<<<QBLOCKS, QTHREADS, 0, stream>>>(z, centers, out, f);
  pkern<<<NB / 256, 256, 0, stream>>>(out, f, out + (size_t)NB * K);
}